// Round 5
// baseline (459.005 us; speedup 1.0000x reference)
//
#include <hip/hip_runtime.h>

typedef float floatx4 __attribute__((ext_vector_type(4)));
typedef _Float16 half_t;
typedef _Float16 halfx8 __attribute__((ext_vector_type(8)));
typedef _Float16 halfx4 __attribute__((ext_vector_type(4)));

#define S_LEN 2048
#define HDIM 3584
#define NHEADS 28
#define NKVH 4
#define GRP 7
#define DHEAD 128
#define KVDIM 512   // NKVH*DHEAD
#define KCHUNK 896  // HDIM/4 (qkv split-K)
#define KHALF 1792  // HDIM/2 (oproj split-K)

// Async global->LDS, 16B per lane. LDS dest is wave-uniform base + lane*16.
__device__ __forceinline__ void load_lds16(const half_t* g, half_t* l) {
    __builtin_amdgcn_global_load_lds(
        (__attribute__((address_space(1))) void*)(g),
        (__attribute__((address_space(3))) void*)(l), 16, 0, 0);
}

// ---------------------------------------------------------------------------
// fp32 -> f16 conversion: hidden + Wq/Wk/Wv (Wo converted later, see
// cvtwo_kernel -- its destination region is busy until postqkv).
// ---------------------------------------------------------------------------
__global__ __launch_bounds__(256) void cvt_kernel(
    const float* __restrict__ hidden, const float* __restrict__ Wq,
    const float* __restrict__ Wk, const float* __restrict__ Wv,
    half_t* __restrict__ hh, half_t* __restrict__ wq, half_t* __restrict__ wk,
    half_t* __restrict__ wv)
{
    int b = blockIdx.x;
    const float* src; half_t* dst; long off;
    if (b < 896)       { src = hidden; dst = hh; off = (long)b * 8192; }
    else if (b < 2464) { src = Wq; dst = wq; off = (long)(b - 896) * 8192; }
    else if (b < 2688) { src = Wk; dst = wk; off = (long)(b - 2464) * 8192; }
    else               { src = Wv; dst = wv; off = (long)(b - 2688) * 8192; }
    #pragma unroll
    for (int i = 0; i < 8; i++) {
        long e = off + i * 1024 + threadIdx.x * 4;
        floatx4 d = *(const floatx4*)&src[e];
        halfx4 h;
        h[0] = (half_t)d[0]; h[1] = (half_t)d[1];
        h[2] = (half_t)d[2]; h[3] = (half_t)d[3];
        *(halfx4*)&dst[e] = h;
    }
}

// fp32 -> f16 for Wo, launched after postqkv (dest aliases dead Pq slices).
__global__ __launch_bounds__(256) void cvtwo_kernel(
    const float* __restrict__ Wo, half_t* __restrict__ wo)
{
    long off = (long)blockIdx.x * 8192;
    #pragma unroll
    for (int i = 0; i < 8; i++) {
        long e = off + i * 1024 + threadIdx.x * 4;
        floatx4 d = *(const floatx4*)&Wo[e];
        halfx4 h;
        h[0] = (half_t)d[0]; h[1] = (half_t)d[1];
        h[2] = (half_t)d[2]; h[3] = (half_t)d[3];
        *(halfx4*)&wo[e] = h;
    }
}

// ---------------------------------------------------------------------------
// 256x256 tile, BK=64, 8-wave (2Mx4N) 8-phase pipelined f16 GEMM.
// C[m][n] = sum_k A[m][k]*B[n][k] (raw; bias applied in fixup passes).
// LDS: A,B each 2 x (256x64) f16 = 128 KiB, XOR-swizzled (slot ^= row&7) on
// ds_read; global_load_lds dest is linear -> inverse permutation applied to
// the per-lane GLOBAL source address.
//
// Reads: 24 ds_read_b128 per wave per K-tile (minimum): B fragments are
// read ONCE (bf0 at p1/p5, bf1 at p2/p6) and held across both M-half
// phases; A halves read at p1/p3 (p5/p7).
// Stage schedule:
//   p1: A1h1,B1h1 <- T(2i+1) | p2: A0h0 <- T(2i+2) | p4: B0h0,A0h1 + vmcnt(6)
//   p5: B0h1 | p7: A1h0 <- T(2i+3) | p8: B1h0 + vmcnt(4)
//   vmcnt(6)@p4 waits {prev p7,p8, this p1} = all of T(2i+1) (read from p5).
//   vmcnt(4)@p8 waits {p2,p4,p5} = all of T(2i+2) (read from next p1).
// WAR: every staged region's last ds_read completed >=1 barrier earlier
// (B regions are register-held after their single read).
// Last iter stages 2 garbage tiles (reads stay in workspace; never consumed).
// OUT_MODE: 1 = f16 row-major, 2 = f16 col-major (ldc=M).
// ---------------------------------------------------------------------------
template<int OUT_MODE>
__device__ __forceinline__ void gemm256(
    const half_t* __restrict__ A, const half_t* __restrict__ B,
    void* __restrict__ Cp,
    long bm, long bn, long ldc, long lda, int K,
    half_t* As, half_t* Bs)
{
    const int tid    = threadIdx.x;
    const int lane   = tid & 63;
    const int wave   = tid >> 6;     // 0..7
    const int wave_m = wave >> 2;    // 0..1
    const int wave_n = wave & 3;     // 0..3
    const int lrow   = lane & 15;
    const int quad   = lane >> 4;
    const int l7     = lane & 7;
    const int sk0    = quad ^ l7;        // swizzled 16B slot, ks=0
    const int sk1    = (4 | quad) ^ l7;  // swizzled 16B slot, ks=1
    const int aw     = wave_m * 64 + lrow;
    const int bw     = wave_n * 32 + lrow;

    // staging: thread t covers LDS row r'=(call base)+(t>>3), 16B slot t&7.
    const int slg = (tid & 7) ^ ((tid >> 3) & 7);
    const half_t* pA = &A[(bm + (tid >> 3)) * lda + slg * 8];
    const half_t* pB = &B[(bn + ((tid >= 256) ? 64 : 0) + ((tid >> 3) & 31)) * lda + slg * 8];
    half_t* dA = As + (long)tid * 8;
    half_t* dB = Bs + (long)tid * 8;

    #define STG_A(PAR,H,KT) do{ \
        const half_t* s_ = pA + (long)(H) * 64 * lda + (long)(KT) * 64; \
        half_t* d_ = dA + (PAR) * 16384 + (H) * 8192; \
        load_lds16(s_, d_); \
        load_lds16(s_ + 128 * lda, d_ + 4096); } while(0)
    #define STG_B(PAR,H,KT) do{ \
        const half_t* s_ = pB + (long)(H) * 32 * lda + (long)(KT) * 64; \
        half_t* d_ = dB + (PAR) * 16384 + (H) * 8192; \
        load_lds16(s_, d_); \
        load_lds16(s_ + 128 * lda, d_ + 4096); } while(0)

    #define ARD(PAR,MH,M,KS) \
        (*(const halfx8*)&As[(PAR)*16384 + ((MH)*128 + aw + (M)*16)*64 + ((KS)?sk1:sk0)*8])
    #define BRD(PAR,NH,N2,KS) \
        (*(const halfx8*)&Bs[(PAR)*16384 + ((NH)*128 + bw + (N2)*16)*64 + ((KS)?sk1:sk0)*8])

    #define BAR() asm volatile("s_barrier" ::: "memory")
    #define VMW4() asm volatile("s_waitcnt vmcnt(4)" ::: "memory")
    #define VMW6() asm volatile("s_waitcnt vmcnt(6)" ::: "memory")

    floatx4 acc[8][4] = {};
    halfx8 af[4][2], bf0[2][2], bf1[2][2];

    #define READ_A(PAR,MH) do{ \
        _Pragma("unroll") \
        for (int m_ = 0; m_ < 4; m_++) { \
            af[m_][0] = ARD(PAR, MH, m_, 0); \
            af[m_][1] = ARD(PAR, MH, m_, 1); } } while(0)
    #define READ_B(PAR,NH,DST) do{ \
        _Pragma("unroll") \
        for (int n_ = 0; n_ < 2; n_++) { \
            DST[n_][0] = BRD(PAR, NH, n_, 0); \
            DST[n_][1] = BRD(PAR, NH, n_, 1); } } while(0)

    #define MFMA16(MH, NH, BF) do { \
        __builtin_amdgcn_s_setprio(1); \
        _Pragma("unroll") \
        for (int ks_ = 0; ks_ < 2; ks_++) \
            _Pragma("unroll") \
            for (int m_ = 0; m_ < 4; m_++) \
                _Pragma("unroll") \
                for (int n_ = 0; n_ < 2; n_++) \
                    acc[(MH)*4 + m_][(NH)*2 + n_] = \
                        __builtin_amdgcn_mfma_f32_16x16x32_f16( \
                            af[m_][ks_], BF[n_][ks_], \
                            acc[(MH)*4 + m_][(NH)*2 + n_], 0, 0, 0); \
        __builtin_amdgcn_s_setprio(0); \
    } while(0)

    // prologue: T0 fully (8 loads) + T1 h0 regions (4 loads);
    // vmcnt(4) -> T0's 8 loads arrived.
    STG_A(0, 0, 0); STG_B(0, 0, 0); STG_A(0, 1, 0); STG_B(0, 1, 0);
    STG_A(1, 0, 1); STG_B(1, 0, 1);
    VMW4(); BAR();

    const int ni = K >> 7;   // 2 K-tiles (BK=64) per iter
    for (int i = 0; i < ni; i++) {
        const int e2 = 2 * i;
        // p1
        READ_A(0, 0); READ_B(0, 0, bf0);
        STG_A(1, 1, e2 + 1); STG_B(1, 1, e2 + 1);
        BAR(); MFMA16(0, 0, bf0); BAR();
        // p2
        READ_B(0, 1, bf1);
        STG_A(0, 0, e2 + 2);
        BAR(); MFMA16(0, 1, bf1); BAR();
        // p3
        READ_A(0, 1);
        BAR(); MFMA16(1, 0, bf0); BAR();
        // p4
        STG_B(0, 0, e2 + 2); STG_A(0, 1, e2 + 2); VMW6();
        BAR(); MFMA16(1, 1, bf1); BAR();
        // p5
        READ_A(1, 0); READ_B(1, 0, bf0);
        STG_B(0, 1, e2 + 2);
        BAR(); MFMA16(0, 0, bf0); BAR();
        // p6
        READ_B(1, 1, bf1);
        BAR(); MFMA16(0, 1, bf1); BAR();
        // p7
        READ_A(1, 1);
        STG_A(1, 0, e2 + 3);
        BAR(); MFMA16(1, 0, bf0); BAR();
        // p8
        STG_B(1, 0, e2 + 3); VMW4();
        BAR(); MFMA16(1, 1, bf1); BAR();
    }

    // Epilogue: C/D layout col=lane&15, row=quad*4+reg
    #pragma unroll
    for (int n = 0; n < 4; n++) {
        long col = bn + wave_n * 64 + n * 16 + lrow;
        #pragma unroll
        for (int m = 0; m < 8; m++) {
            long rbase = bm + wave_m * 128 + m * 16 + quad * 4;
            if constexpr (OUT_MODE == 2) {
                halfx4 h;
                #pragma unroll
                for (int r = 0; r < 4; r++)
                    h[r] = (half_t)acc[m][n][r];
                *(halfx4*)&((half_t*)Cp)[col * ldc + rbase] = h;
            } else {
                #pragma unroll
                for (int r = 0; r < 4; r++)
                    ((half_t*)Cp)[(rbase + r) * ldc + col] = (half_t)acc[m][n][r];
            }
        }
    }
    #undef STG_A
    #undef STG_B
    #undef ARD
    #undef BRD
    #undef BAR
    #undef VMW4
    #undef VMW6
    #undef READ_A
    #undef READ_B
    #undef MFMA16
}

// Fused QKV projection, split-K=4: grid (8, 18, 4); x = row-tile,
// y = col-tile (y<14 -> Q, <16 -> K, else V^T), z = K-chunk (896).
// 576 equal units -> ~3 rounds on 256 CUs (vs 1 round of 144 = 56% fill).
// Writes raw f16 partials; reduction+bias+rope in postqkv_kernel.
__global__ __launch_bounds__(512, 2) void qkv_kernel(
    const half_t* __restrict__ hh,
    const half_t* __restrict__ wq, const half_t* __restrict__ wk,
    const half_t* __restrict__ wv,
    half_t* __restrict__ Pq, half_t* __restrict__ Pk, half_t* __restrict__ Pv)
{
    __shared__ __align__(16) half_t As[2 * 16384];
    __shared__ __align__(16) half_t Bs[2 * 16384];
    int by = blockIdx.y;
    int z  = blockIdx.z;
    long koff = (long)z * KCHUNK;
    long bm = (long)blockIdx.x * 256;
    const half_t* Az = hh + koff;
    if (by < 14) {
        gemm256<1>(Az, wq + koff, Pq + (size_t)z * S_LEN * HDIM,
                   bm, (long)by * 256, HDIM, HDIM, KCHUNK, As, Bs);
    } else if (by < 16) {
        gemm256<1>(Az, wk + koff, Pk + (size_t)z * S_LEN * KVDIM,
                   bm, (long)(by - 14) * 256, KVDIM, HDIM, KCHUNK, As, Bs);
    } else {
        gemm256<2>(Az, wv + koff, Pv + (size_t)z * KVDIM * S_LEN,
                   bm, (long)(by - 16) * 256, S_LEN, HDIM, KCHUNK, As, Bs);
    }
}

// Output projection, split-K=2: grid (8, 14, 2); f16 partials.
__global__ __launch_bounds__(512, 2) void oproj_kernel(
    const half_t* __restrict__ o, const half_t* __restrict__ wo,
    half_t* __restrict__ Po)
{
    __shared__ __align__(16) half_t As[2 * 16384];
    __shared__ __align__(16) half_t Bs[2 * 16384];
    int z = blockIdx.z;
    long koff = (long)z * KHALF;
    gemm256<1>(o + koff, wo + koff,
               Po + (size_t)z * S_LEN * HDIM,
               (long)blockIdx.x * 256, (long)blockIdx.y * 256,
               HDIM, HDIM, KHALF, As, Bs);
}

// Sum the two f16 oproj partials into the final fp32 output.
__global__ __launch_bounds__(256) void oreduce_kernel(
    const half_t* __restrict__ Po, float* __restrict__ out)
{
    long i = ((long)blockIdx.x * 256 + threadIdx.x) * 4;
    halfx4 a = *(const halfx4*)&Po[i];
    halfx4 b = *(const halfx4*)&Po[(size_t)S_LEN * HDIM + i];
    floatx4 r;
    #pragma unroll
    for (int j = 0; j < 4; j++)
        r[j] = (float)a[j] + (float)b[j];
    *(floatx4*)&out[i] = r;
}

// Split-K(4) reduction + bias + RoPE (q scaled by 1/sqrt(D)) + v-bias.
// q/k/vt alias partial slice 0 (identical layout, element-exact in-place:
// each thread reads all 4 slices of its elements before writing).
// NO __restrict__ here: outputs alias inputs by design.
// Blocks: [0,3584) Q, [3584,4096) K, [4096,5120) V.
__global__ __launch_bounds__(256) void postqkv_kernel(
    const half_t* Pq, const half_t* Pk, const half_t* Pv,
    const float* bq, const float* bk, const float* bv,
    const float* ct, const float* st,
    half_t* q, half_t* k, half_t* vt)
{
    const float scale = 0.08838834764831845f; // 128^-0.5
    int b = blockIdx.x, t = threadIdx.x;
    if (b < 3584) {           // Q: 2048 rows x 28 heads x 16 quad-pairs
        int item = b * 256 + t;
        int s = item / 448;
        int rem = item % 448;
        int h = rem >> 4, d0 = (rem & 15) * 4;
        long c = (long)h * 128 + d0;
        long base = (long)s * HDIM + c;
        float u[4], w[4];
        #pragma unroll
        for (int i = 0; i < 4; i++) { u[i] = bq[c + i]; w[i] = bq[c + 64 + i]; }
        #pragma unroll
        for (int z = 0; z < 4; z++) {
            const half_t* p = Pq + (size_t)z * S_LEN * HDIM + base;
            halfx4 a = *(const halfx4*)p;
            halfx4 bb = *(const halfx4*)(p + 64);
            #pragma unroll
            for (int i = 0; i < 4; i++) { u[i] += (float)a[i]; w[i] += (float)bb[i]; }
        }
        floatx4 cs = *(const floatx4*)&ct[s * 128 + d0];
        floatx4 sn = *(const floatx4*)&st[s * 128 + d0];
        halfx4 o1, o2;
        #pragma unroll
        for (int i = 0; i < 4; i++) {
            o1[i] = (half_t)((u[i] * cs[i] - w[i] * sn[i]) * scale);
            o2[i] = (half_t)((w[i] * cs[i] + u[i] * sn[i]) * scale);
        }
        *(halfx4*)&q[base] = o1;
        *(halfx4*)&q[base + 64] = o2;
    } else if (b < 4096) {    // K: 2048 rows x 4 heads x 16
        int item = (b - 3584) * 256 + t;
        int s = item >> 6;
        int rem = item & 63;
        int h = rem >> 4, d0 = (rem & 15) * 4;
        long c = (long)h * 128 + d0;
        long base = (long)s * KVDIM + c;
        float u[4], w[4];
        #pragma unroll
        for (int i = 0; i < 4; i++) { u[i] = bk[c + i]; w[i] = bk[c + 64 + i]; }
        #pragma unroll
        for (int z = 0; z < 4; z++) {
            const half_t* p = Pk + (size_t)z * S_LEN * KVDIM + base;
            halfx4 a = *(const halfx4*)p;
            halfx4 bb = *(const halfx4*)(p + 64);
            #pragma unroll
            for (int i = 0; i < 4; i++) { u[i] += (float)a[i]; w[i] += (float)bb[i]; }
        }
        floatx4 cs = *(const floatx4*)&ct[s * 128 + d0];
        floatx4 sn = *(const floatx4*)&st[s * 128 + d0];
        halfx4 o1, o2;
        #pragma unroll
        for (int i = 0; i < 4; i++) {
            o1[i] = (half_t)(u[i] * cs[i] - w[i] * sn[i]);
            o2[i] = (half_t)(w[i] * cs[i] + u[i] * sn[i]);
        }
        *(halfx4*)&k[base] = o1;
        *(halfx4*)&k[base + 64] = o2;
    } else {                  // V^T: 512 cols x 512 s-quads (col-major)
        int item = (b - 4096) * 256 + t;
        int col = item >> 9;
        int s4 = (item & 511) * 4;
        long base = (long)col * S_LEN + s4;
        float bvv = bv[col];
        float u[4] = {bvv, bvv, bvv, bvv};
        #pragma unroll
        for (int z = 0; z < 4; z++) {
            halfx4 a = *(const halfx4*)(Pv + (size_t)z * KVDIM * S_LEN + base);
            #pragma unroll
            for (int i = 0; i < 4; i++) u[i] += (float)a[i];
        }
        halfx4 o;
        #pragma unroll
        for (int i = 0; i < 4; i++) o[i] = (half_t)u[i];
        *(halfx4*)&vt[base] = o;
    }
}

// Flash attention, barrier-free. Block = (64 q rows, 1 head), 4 independent
// waves x 16 rows. 64-key chunks; K and V^T fragments loaded directly from
// global (L2-resident); only the per-wave P C->A roundtrip uses LDS.
__global__ __launch_bounds__(256) void attn_kernel(
    const half_t* __restrict__ q, const half_t* __restrict__ k,
    const half_t* __restrict__ vt, const int* __restrict__ doc,
    half_t* __restrict__ o)
{
    constexpr int PS = 72; // 64 keys + 8 pad
    __shared__ half_t Ps[4][16 * PS];

    const int tid  = threadIdx.x;
    const int lane = tid & 63;
    const int wave = tid >> 6;
    const int head = blockIdx.y;
    const int kvh  = head / GRP;
    const int qbase = blockIdx.x * 64;
    const int lrow = lane & 15;
    const int quad = lane >> 4;
    const int k0 = quad * 8;

    const int qrow = qbase + wave * 16 + lrow;
    halfx8 qf[4];
    #pragma unroll
    for (int kk = 0; kk < 4; kk++)
        qf[kk] = *(const halfx8*)&q[(long)qrow * HDIM + head * 128 + kk * 32 + k0];

    int qdoc[4], qpos[4];
    #pragma unroll
    for (int r = 0; r < 4; r++) {
        qpos[r] = qbase + wave * 16 + quad * 4 + r;
        qdoc[r] = doc[qpos[r]];
    }

    // lower_bound(doc, doc[qbase]): skip keys before this tile's earliest doc
    int tgt = doc[qbase];
    int lo = 0, hi = qbase;
    while (lo < hi) { int mid = (lo + hi) >> 1; if (doc[mid] < tgt) lo = mid + 1; else hi = mid; }
    const int kc0 = lo & ~63;

    float m_r[4], l_r[4];
    floatx4 oacc[8] = {};
    #pragma unroll
    for (int r = 0; r < 4; r++) { m_r[r] = -INFINITY; l_r[r] = 0.0f; }

    for (int kbase = kc0; kbase <= qbase; kbase += 64) {
        floatx4 sacc[4] = {};
        #pragma unroll
        for (int s = 0; s < 4; s++) {
            const half_t* kp = &k[(long)(kbase + s * 16 + lrow) * KVDIM + kvh * 128];
            #pragma unroll
            for (int kk = 0; kk < 4; kk++) {
                halfx8 bk = *(const halfx8*)&kp[kk * 32 + k0];
                sacc[s] = __builtin_amdgcn_mfma_f32_16x16x32_f16(qf[kk], bk, sacc[s], 0, 0, 0);
            }
        }

        int kpix[4], kd[4];
        #pragma unroll
        for (int s = 0; s < 4; s++) {
            kpix[s] = kbase + s * 16 + lrow;
            kd[s] = doc[kpix[s]];
        }
        float pk[4][4];
        float alpha[4];
        #pragma unroll
        for (int r = 0; r < 4; r++) {
            float sv[4];
            float mx = -INFINITY;
            #pragma unroll
            for (int s = 0; s < 4; s++) {
                float x = sacc[s][r];
                bool valid = (kpix[s] <= qpos[r]) && (kd[s] == qdoc[r]);
                x = valid ? x : -INFINITY;
                sv[s] = x;
                mx = fmaxf(mx, x);
            }
            #pragma unroll
            for (int off = 1; off < 16; off <<= 1)
                mx = fmaxf(mx, __shfl_xor(mx, off));
            float mnew = fmaxf(m_r[r], mx);
            bool ninf = (mnew != -INFINITY);
            alpha[r] = ninf ? __expf(m_r[r] - mnew) : 1.0f;
            float sm = 0.0f;
            #pragma unroll
            for (int s = 0; s < 4; s++) {
                float p = ninf ? __expf(sv[s] - mnew) : 0.0f;
                pk[s][r] = p;
                sm += p;
            }
            #pragma unroll
            for (int off = 1; off < 16; off <<= 1)
                sm += __shfl_xor(sm, off);
            l_r[r] = l_r[r] * alpha[r] + sm;
            m_r[r] = mnew;
        }

        #pragma unroll
        for (int t = 0; t < 8; t++)
            #pragma unroll
            for (int r = 0; r < 4; r++)
                oacc[t][r] *= alpha[r];

        #pragma unroll
        for (int s = 0; s < 4; s++)
            #pragma unroll
            for (int r = 0; r < 4; r++)
                Ps[wave][(quad * 4 + r) * PS + s * 16 + lrow] = (half_t)pk[s][r];
        halfx8 pa0 = *(const halfx8*)&Ps[wave][lrow * PS + k0];
        halfx8 pa1 = *(const halfx8*)&Ps[wave][lrow * PS + 32 + k0];

        #pragma unroll
        for (int t = 0; t < 8; t++) {
            const half_t* vp = &vt[(long)(kvh * 128 + t * 16 + lrow) * S_LEN + kbase];
            halfx8 b0 = *(const halfx8*)&vp[k0];
            halfx8 b1 = *(const halfx8*)&vp[32 + k0];
            oacc[t] = __builtin_amdgcn_mfma_f32_16x16x32_f16(pa0, b0, oacc[t], 0, 0, 0);
            oacc[t] = __builtin_amdgcn_mfma_f32_16x16x32_f16(pa1, b1, oacc[t], 0, 0, 0);
        }
    }

    #pragma unroll
    for (int r = 0; r < 4; r++) {
        float inv = 1.0f / l_r[r];
        long row = qpos[r];
        #pragma unroll
        for (int t = 0; t < 8; t++)
            o[row * HDIM + head * 128 + t * 16 + lrow] = (half_t)(oacc[t][r] * inv);
    }
}

extern "C" void kernel_launch(void* const* d_in, const int* in_sizes, int n_in,
                              void* d_out, int out_size, void* d_ws, size_t ws_size,
                              hipStream_t stream) {
    const float* hidden = (const float*)d_in[0];
    const float* cosT   = (const float*)d_in[1];
    const float* sinT   = (const float*)d_in[2];
    const int*   doc    = (const int*)d_in[3];
    // d_in[4] = position_ids (unused; cos/sin precomputed)
    const float* Wq = (const float*)d_in[5];
    const float* bq = (const float*)d_in[6];
    const float* Wk = (const float*)d_in[7];
    const float* bk = (const float*)d_in[8];
    const float* Wv = (const float*)d_in[9];
    const float* bv = (const float*)d_in[10];
    const float* Wo = (const float*)d_in[11];
    float* out = (float*)d_out;

    // f16 workspace layout (halves), 123.2 MB total (< 130 MB proven):
    //   [hh][wqh][wkh][wvh][Pq x4][Pk x4][Pv x4]
    // Liveness-based aliases:
    //   q/k/vt = partial slice 0 (postqkv reduces in place)
    //   o   = hh            (dead after qkv)
    //   woh = Pq slice 1..  (slices 1-3 dead after postqkv; Wo converted
    //                        by cvtwo_kernel AFTER postqkv)
    //   Po  = wqh           (weights dead after qkv; 14.7M <= 16.5M)
    // GEMM garbage prefetch past each operand lands in the next live region.
    half_t* hh  = (half_t*)d_ws;
    half_t* wqh = hh  + (size_t)S_LEN * HDIM;
    half_t* wkh = wqh + (size_t)HDIM * HDIM;
    half_t* wvh = wkh + (size_t)KVDIM * HDIM;
    half_t* Pq  = wvh + (size_t)KVDIM * HDIM;      // [4][S][HDIM]
    half_t* Pk  = Pq  + (size_t)4 * S_LEN * HDIM;  // [4][S][KVDIM]
    half_t* Pv  = Pk  + (size_t)4 * S_LEN * KVDIM; // [4][KVDIM][S]
    half_t* q   = Pq;   // in-place reduce targets
    half_t* k   = Pk;
    half_t* vt  = Pv;
    half_t* o   = hh;
    half_t* woh = Pq + (size_t)S_LEN * HDIM;  // slices 1-2 region
    half_t* Po  = wqh;

    cvt_kernel<<<2912, 256, 0, stream>>>(hidden, Wq, Wk, Wv, hh, wqh, wkh, wvh);
    qkv_kernel<<<dim3(8, 18, 4), 512, 0, stream>>>(hh, wqh, wkh, wvh, Pq, Pk, Pv);
    postqkv_kernel<<<5120, 256, 0, stream>>>(Pq, Pk, Pv, bq, bk, bv, cosT, sinT, q, k, vt);
    cvtwo_kernel<<<1568, 256, 0, stream>>>(Wo, woh);
    attn_kernel<<<dim3(32, NHEADS), 256, 0, stream>>>(q, k, vt, doc, o);
    oproj_kernel<<<dim3(8, 14, 2), 512, 0, stream>>>(o, woh, Po);
    oreduce_kernel<<<7168, 256, 0, stream>>>(Po, out);
}

// Round 6
// 449.103 us; speedup vs baseline: 1.0220x; 1.0220x over previous
//
#include <hip/hip_runtime.h>

typedef float floatx4 __attribute__((ext_vector_type(4)));
typedef _Float16 half_t;
typedef _Float16 halfx8 __attribute__((ext_vector_type(8)));
typedef _Float16 halfx4 __attribute__((ext_vector_type(4)));

#define S_LEN 2048
#define HDIM 3584
#define NHEADS 28
#define NKVH 4
#define GRP 7
#define DHEAD 128
#define KVDIM 512   // NKVH*DHEAD
#define KHALF 1792  // HDIM/2 (oproj split-K)

// Async global->LDS, 16B per lane. LDS dest is wave-uniform base + lane*16.
__device__ __forceinline__ void load_lds16(const half_t* g, half_t* l) {
    __builtin_amdgcn_global_load_lds(
        (__attribute__((address_space(1))) void*)(g),
        (__attribute__((address_space(3))) void*)(l), 16, 0, 0);
}

// ---------------------------------------------------------------------------
// fp32 -> f16 conversion for hidden + all weights, one launch.
// ---------------------------------------------------------------------------
__global__ __launch_bounds__(256) void cvt_kernel(
    const float* __restrict__ hidden, const float* __restrict__ Wq,
    const float* __restrict__ Wk, const float* __restrict__ Wv,
    const float* __restrict__ Wo,
    half_t* __restrict__ hh, half_t* __restrict__ wq, half_t* __restrict__ wk,
    half_t* __restrict__ wv, half_t* __restrict__ wo)
{
    int b = blockIdx.x;
    const float* src; half_t* dst; long off;
    if (b < 896)       { src = hidden; dst = hh; off = (long)b * 8192; }
    else if (b < 2464) { src = Wq; dst = wq; off = (long)(b - 896) * 8192; }
    else if (b < 2688) { src = Wk; dst = wk; off = (long)(b - 2464) * 8192; }
    else if (b < 2912) { src = Wv; dst = wv; off = (long)(b - 2688) * 8192; }
    else               { src = Wo; dst = wo; off = (long)(b - 2912) * 8192; }
    #pragma unroll
    for (int i = 0; i < 8; i++) {
        long e = off + i * 1024 + threadIdx.x * 4;
        floatx4 d = *(const floatx4*)&src[e];
        halfx4 h;
        h[0] = (half_t)d[0]; h[1] = (half_t)d[1];
        h[2] = (half_t)d[2]; h[3] = (half_t)d[3];
        *(halfx4*)&dst[e] = h;
    }
}

// ---------------------------------------------------------------------------
// 256x256 tile, BK=64, 8-wave (2Mx4N) 8-phase pipelined f16 GEMM.
// C[m][n] = sum_k A[m][k]*B[n][k] (+bias[n]).
// LDS: A,B each 2 x (256x64) f16 = 128 KiB, XOR-swizzled (slot ^= row&7) on
// ds_read; global_load_lds dest is linear -> inverse permutation applied to
// the per-lane GLOBAL source address.
// Reads: 24 ds_read_b128 per wave per K-tile: B fragments read ONCE
// (bf0 p1/p5, bf1 p2/p6), held across both M-half phases; A at p1/p3/p5/p7.
// Stage schedule (verified on HW in R3/R5):
//   p1: A1h1,B1h1 <- T(2i+1) | p2: A0h0 <- T(2i+2) | p4: B0h0,A0h1 + vmcnt(6)
//   p5: B0h1 | p7: A1h0 <- T(2i+3) | p8: B1h0 + vmcnt(4)
// Last iter stages 2 garbage tiles (reads stay in workspace; never consumed).
// OUT_MODE: 1 = f16 row-major, 2 = f16 col-major (ldc=M).
// ---------------------------------------------------------------------------
template<int OUT_MODE, bool HAS_BIAS>
__device__ __forceinline__ void gemm256(
    const half_t* __restrict__ A, const half_t* __restrict__ B,
    const float* __restrict__ bias, void* __restrict__ Cp,
    long bm, long bn, long ldc, long lda, int K,
    half_t* As, half_t* Bs)
{
    const int tid    = threadIdx.x;
    const int lane   = tid & 63;
    const int wave   = tid >> 6;     // 0..7
    const int wave_m = wave >> 2;    // 0..1
    const int wave_n = wave & 3;     // 0..3
    const int lrow   = lane & 15;
    const int quad   = lane >> 4;
    const int l7     = lane & 7;
    const int sk0    = quad ^ l7;        // swizzled 16B slot, ks=0
    const int sk1    = (4 | quad) ^ l7;  // swizzled 16B slot, ks=1
    const int aw     = wave_m * 64 + lrow;
    const int bw     = wave_n * 32 + lrow;

    // staging: thread t covers LDS row r'=(call base)+(t>>3), 16B slot t&7.
    const int slg = (tid & 7) ^ ((tid >> 3) & 7);
    const half_t* pA = &A[(bm + (tid >> 3)) * lda + slg * 8];
    const half_t* pB = &B[(bn + ((tid >= 256) ? 64 : 0) + ((tid >> 3) & 31)) * lda + slg * 8];
    half_t* dA = As + (long)tid * 8;
    half_t* dB = Bs + (long)tid * 8;

    #define STG_A(PAR,H,KT) do{ \
        const half_t* s_ = pA + (long)(H) * 64 * lda + (long)(KT) * 64; \
        half_t* d_ = dA + (PAR) * 16384 + (H) * 8192; \
        load_lds16(s_, d_); \
        load_lds16(s_ + 128 * lda, d_ + 4096); } while(0)
    #define STG_B(PAR,H,KT) do{ \
        const half_t* s_ = pB + (long)(H) * 32 * lda + (long)(KT) * 64; \
        half_t* d_ = dB + (PAR) * 16384 + (H) * 8192; \
        load_lds16(s_, d_); \
        load_lds16(s_ + 128 * lda, d_ + 4096); } while(0)

    #define ARD(PAR,MH,M,KS) \
        (*(const halfx8*)&As[(PAR)*16384 + ((MH)*128 + aw + (M)*16)*64 + ((KS)?sk1:sk0)*8])
    #define BRD(PAR,NH,N2,KS) \
        (*(const halfx8*)&Bs[(PAR)*16384 + ((NH)*128 + bw + (N2)*16)*64 + ((KS)?sk1:sk0)*8])

    #define BAR() asm volatile("s_barrier" ::: "memory")
    #define VMW4() asm volatile("s_waitcnt vmcnt(4)" ::: "memory")
    #define VMW6() asm volatile("s_waitcnt vmcnt(6)" ::: "memory")

    floatx4 acc[8][4] = {};
    halfx8 af[4][2], bf0[2][2], bf1[2][2];

    #define READ_A(PAR,MH) do{ \
        _Pragma("unroll") \
        for (int m_ = 0; m_ < 4; m_++) { \
            af[m_][0] = ARD(PAR, MH, m_, 0); \
            af[m_][1] = ARD(PAR, MH, m_, 1); } } while(0)
    #define READ_B(PAR,NH,DST) do{ \
        _Pragma("unroll") \
        for (int n_ = 0; n_ < 2; n_++) { \
            DST[n_][0] = BRD(PAR, NH, n_, 0); \
            DST[n_][1] = BRD(PAR, NH, n_, 1); } } while(0)

    #define MFMA16(MH, NH, BF) do { \
        __builtin_amdgcn_s_setprio(1); \
        _Pragma("unroll") \
        for (int ks_ = 0; ks_ < 2; ks_++) \
            _Pragma("unroll") \
            for (int m_ = 0; m_ < 4; m_++) \
                _Pragma("unroll") \
                for (int n_ = 0; n_ < 2; n_++) \
                    acc[(MH)*4 + m_][(NH)*2 + n_] = \
                        __builtin_amdgcn_mfma_f32_16x16x32_f16( \
                            af[m_][ks_], BF[n_][ks_], \
                            acc[(MH)*4 + m_][(NH)*2 + n_], 0, 0, 0); \
        __builtin_amdgcn_s_setprio(0); \
    } while(0)

    // prologue: T0 fully (8 loads) + T1 h0 regions (4 loads);
    // vmcnt(4) -> T0's 8 loads arrived.
    STG_A(0, 0, 0); STG_B(0, 0, 0); STG_A(0, 1, 0); STG_B(0, 1, 0);
    STG_A(1, 0, 1); STG_B(1, 0, 1);
    VMW4(); BAR();

    const int ni = K >> 7;   // 2 K-tiles (BK=64) per iter
    for (int i = 0; i < ni; i++) {
        const int e2 = 2 * i;
        // p1
        READ_A(0, 0); READ_B(0, 0, bf0);
        STG_A(1, 1, e2 + 1); STG_B(1, 1, e2 + 1);
        BAR(); MFMA16(0, 0, bf0); BAR();
        // p2
        READ_B(0, 1, bf1);
        STG_A(0, 0, e2 + 2);
        BAR(); MFMA16(0, 1, bf1); BAR();
        // p3
        READ_A(0, 1);
        BAR(); MFMA16(1, 0, bf0); BAR();
        // p4
        STG_B(0, 0, e2 + 2); STG_A(0, 1, e2 + 2); VMW6();
        BAR(); MFMA16(1, 1, bf1); BAR();
        // p5
        READ_A(1, 0); READ_B(1, 0, bf0);
        STG_B(0, 1, e2 + 2);
        BAR(); MFMA16(0, 0, bf0); BAR();
        // p6
        READ_B(1, 1, bf1);
        BAR(); MFMA16(0, 1, bf1); BAR();
        // p7
        READ_A(1, 1);
        STG_A(1, 0, e2 + 3);
        BAR(); MFMA16(1, 0, bf0); BAR();
        // p8
        STG_B(1, 0, e2 + 3); VMW4();
        BAR(); MFMA16(1, 1, bf1); BAR();
    }

    // Epilogue: C/D layout col=lane&15, row=quad*4+reg
    #pragma unroll
    for (int n = 0; n < 4; n++) {
        long col = bn + wave_n * 64 + n * 16 + lrow;
        float bvv = HAS_BIAS ? bias[col] : 0.0f;
        #pragma unroll
        for (int m = 0; m < 8; m++) {
            long rbase = bm + wave_m * 128 + m * 16 + quad * 4;
            if constexpr (OUT_MODE == 2) {
                halfx4 h;
                #pragma unroll
                for (int r = 0; r < 4; r++)
                    h[r] = (half_t)(acc[m][n][r] + bvv);
                *(halfx4*)&((half_t*)Cp)[col * ldc + rbase] = h;
            } else {
                #pragma unroll
                for (int r = 0; r < 4; r++)
                    ((half_t*)Cp)[(rbase + r) * ldc + col] = (half_t)(acc[m][n][r] + bvv);
            }
        }
    }
    #undef STG_A
    #undef STG_B
    #undef ARD
    #undef BRD
    #undef BAR
    #undef VMW4
    #undef VMW6
    #undef READ_A
    #undef READ_B
    #undef MFMA16
}

// Fused QKV projection: grid (8, 18); x = row-tile, y = col-tile:
// y<14 -> Q, y<16 -> K, else V^T. Full-K, bias fused in epilogue.
__global__ __launch_bounds__(512, 2) void qkv_kernel(
    const half_t* __restrict__ hh,
    const half_t* __restrict__ wq, const float* __restrict__ bq,
    const half_t* __restrict__ wk, const float* __restrict__ bk,
    const half_t* __restrict__ wv, const float* __restrict__ bv,
    half_t* __restrict__ q, half_t* __restrict__ k, half_t* __restrict__ vt)
{
    __shared__ __align__(16) half_t As[2 * 16384];
    __shared__ __align__(16) half_t Bs[2 * 16384];
    int by = blockIdx.y;
    long bm = (long)blockIdx.x * 256;
    if (by < 14) {
        gemm256<1, true>(hh, wq, bq, q, bm, (long)by * 256, HDIM, HDIM, HDIM, As, Bs);
    } else if (by < 16) {
        gemm256<1, true>(hh, wk, bk, k, bm, (long)(by - 14) * 256, KVDIM, HDIM, HDIM, As, Bs);
    } else {
        gemm256<2, true>(hh, wv, bv, vt, bm, (long)(by - 16) * 256, S_LEN, HDIM, HDIM, As, Bs);
    }
}

// Output projection, split-K=2: grid (8, 14, 2); f16 partials.
__global__ __launch_bounds__(512, 2) void oproj_kernel(
    const half_t* __restrict__ o, const half_t* __restrict__ wo,
    half_t* __restrict__ Po)
{
    __shared__ __align__(16) half_t As[2 * 16384];
    __shared__ __align__(16) half_t Bs[2 * 16384];
    int z = blockIdx.z;
    long koff = (long)z * KHALF;
    gemm256<1, false>(o + koff, wo + koff, nullptr,
                      Po + (size_t)z * S_LEN * HDIM,
                      (long)blockIdx.x * 256, (long)blockIdx.y * 256,
                      HDIM, HDIM, KHALF, As, Bs);
}

// Sum the two f16 oproj partials into the final fp32 output.
__global__ __launch_bounds__(256) void oreduce_kernel(
    const half_t* __restrict__ Po, float* __restrict__ out)
{
    long i = ((long)blockIdx.x * 256 + threadIdx.x) * 4;
    halfx4 a = *(const halfx4*)&Po[i];
    halfx4 b = *(const halfx4*)&Po[(size_t)S_LEN * HDIM + i];
    floatx4 r;
    #pragma unroll
    for (int j = 0; j < 4; j++)
        r[j] = (float)a[j] + (float)b[j];
    *(floatx4*)&out[i] = r;
}

// In-place RoPE on q (with 1/sqrt(D) scale folded in) and k.
__global__ __launch_bounds__(256) void rope_kernel(
    half_t* __restrict__ q, half_t* __restrict__ k,
    const float* __restrict__ ct, const float* __restrict__ st)
{
    const float scale = 0.08838834764831845f; // 128^-0.5
    int idx = blockIdx.x * 256 + threadIdx.x;
    const int QP = S_LEN * NHEADS * 64;
    half_t* base; int s, d; float sc;
    if (idx < QP) {
        s = idx / (NHEADS * 64);
        int rem = idx % (NHEADS * 64);
        int h = rem >> 6; d = rem & 63;
        base = q + (long)s * HDIM + h * 128 + d;
        sc = scale;
    } else {
        int j = idx - QP;
        s = j / (NKVH * 64);
        int rem = j % (NKVH * 64);
        int h = rem >> 6; d = rem & 63;
        base = k + (long)s * KVDIM + h * 128 + d;
        sc = 1.0f;
    }
    float c = ct[s * 128 + d], sn = st[s * 128 + d];
    float x1 = (float)base[0], x2 = (float)base[64];
    base[0]  = (half_t)((x1 * c - x2 * sn) * sc);
    base[64] = (half_t)((x2 * c + x1 * sn) * sc);
}

// Flash attention, barrier-free, SWAPPED QK^T: sacc = mfma(K, Q) so each
// lane owns ONE q-row (lrow) and 16 of the 64 key-scores -> softmax is
// in-lane + 2 shfl_xor (vs 32 shfl serial chains before).
// doc_ids are SORTED, so (doc[k]==doc[q] && k<=q) <=> loq <= k <= q with
// loq = lower_bound(doc, doc[q]) -- zero doc loads in the chunk loop.
// Block = (64 q rows, 1 head), 4 independent waves x 16 rows.
__global__ __launch_bounds__(256) void attn_kernel(
    const half_t* __restrict__ q, const half_t* __restrict__ k,
    const half_t* __restrict__ vt, const int* __restrict__ doc,
    half_t* __restrict__ o)
{
    constexpr int PS = 72; // 64 keys + 8 pad
    __shared__ half_t Ps[4][16 * PS];

    const int tid  = threadIdx.x;
    const int lane = tid & 63;
    const int wave = tid >> 6;
    const int head = blockIdx.y;
    const int kvh  = head / GRP;
    const int qbase = blockIdx.x * 64;
    const int lrow = lane & 15;
    const int quad = lane >> 4;
    const int k0 = quad * 8;

    const int qrow = qbase + wave * 16 + lrow;  // this lane's q-row
    halfx8 qf[4];
    #pragma unroll
    for (int kk = 0; kk < 4; kk++)
        qf[kk] = *(const halfx8*)&q[(long)qrow * HDIM + head * 128 + kk * 32 + k0];

    // per-lane doc window start: loq = lower_bound(doc, doc[qrow])
    const int qd = doc[qrow];
    int lo = 0, hi = qrow;
    while (lo < hi) { int mid = (lo + hi) >> 1; if (doc[mid] < qd) lo = mid + 1; else hi = mid; }
    const int loq = lo;

    // block-level first chunk: lower_bound(doc, doc[qbase]) (doc sorted ->
    // min loq over the block is at the smallest q).
    int tgt = doc[qbase];
    int l2 = 0, h2 = qbase;
    while (l2 < h2) { int mid = (l2 + h2) >> 1; if (doc[mid] < tgt) l2 = mid + 1; else h2 = mid; }
    const int kc0 = l2 & ~63;

    float m_s = -INFINITY, l_s = 0.0f;
    floatx4 oacc[8] = {};

    for (int kbase = kc0; kbase <= qbase; kbase += 64) {
        // QK^T swapped: A = K-frag (row=key), B = Q-frag (col=q).
        floatx4 sacc[4] = {};
        __builtin_amdgcn_s_setprio(1);
        #pragma unroll
        for (int s = 0; s < 4; s++) {
            const half_t* kp = &k[(long)(kbase + s * 16 + lrow) * KVDIM + kvh * 128];
            #pragma unroll
            for (int kk = 0; kk < 4; kk++) {
                halfx8 kf = *(const halfx8*)&kp[kk * 32 + k0];
                sacc[s] = __builtin_amdgcn_mfma_f32_16x16x32_f16(kf, qf[kk], sacc[s], 0, 0, 0);
            }
        }
        __builtin_amdgcn_s_setprio(0);
        // sacc[s][r] = score(key = kbase + s*16 + quad*4 + r, q = qrow)

        // masked online softmax, per-lane q
        float sv[4][4];
        float mx = -INFINITY;
        #pragma unroll
        for (int s = 0; s < 4; s++)
            #pragma unroll
            for (int r = 0; r < 4; r++) {
                int kpix = kbase + s * 16 + quad * 4 + r;
                float x = sacc[s][r];
                bool valid = (kpix >= loq) && (kpix <= qrow);
                x = valid ? x : -INFINITY;
                sv[s][r] = x;
                mx = fmaxf(mx, x);
            }
        mx = fmaxf(mx, __shfl_xor(mx, 16));
        mx = fmaxf(mx, __shfl_xor(mx, 32));
        float mnew = fmaxf(m_s, mx);
        bool ninf = (mnew != -INFINITY);
        float alpha = ninf ? __expf(m_s - mnew) : 1.0f;
        float sm = 0.0f;
        halfx4 ph[4];
        #pragma unroll
        for (int s = 0; s < 4; s++)
            #pragma unroll
            for (int r = 0; r < 4; r++) {
                float p = ninf ? __expf(sv[s][r] - mnew) : 0.0f;
                ph[s][r] = (half_t)p;
                sm += p;
            }
        sm += __shfl_xor(sm, 16);
        sm += __shfl_xor(sm, 32);
        l_s = l_s * alpha + sm;
        m_s = mnew;

        // broadcast alpha from lane-layout (q=lrow) to oacc layout (q=quad*4+r)
        float ash[4];
        #pragma unroll
        for (int r = 0; r < 4; r++)
            ash[r] = __shfl(alpha, quad * 4 + r, 16);
        #pragma unroll
        for (int t = 0; t < 8; t++)
            #pragma unroll
            for (int r = 0; r < 4; r++)
                oacc[t][r] *= ash[r];

        // P -> LDS (4 x ds_write_b64; keys quad*4..+3 of each s-tile)
        #pragma unroll
        for (int s = 0; s < 4; s++)
            *(halfx4*)&Ps[wave][lrow * PS + s * 16 + quad * 4] = ph[s];
        halfx8 pa0 = *(const halfx8*)&Ps[wave][lrow * PS + k0];
        halfx8 pa1 = *(const halfx8*)&Ps[wave][lrow * PS + 32 + k0];

        __builtin_amdgcn_s_setprio(1);
        #pragma unroll
        for (int t = 0; t < 8; t++) {
            const half_t* vp = &vt[(long)(kvh * 128 + t * 16 + lrow) * S_LEN + kbase];
            halfx8 b0 = *(const halfx8*)&vp[k0];
            halfx8 b1 = *(const halfx8*)&vp[32 + k0];
            oacc[t] = __builtin_amdgcn_mfma_f32_16x16x32_f16(pa0, b0, oacc[t], 0, 0, 0);
            oacc[t] = __builtin_amdgcn_mfma_f32_16x16x32_f16(pa1, b1, oacc[t], 0, 0, 0);
        }
        __builtin_amdgcn_s_setprio(0);
    }

    // broadcast l to oacc layout and write
    #pragma unroll
    for (int r = 0; r < 4; r++) {
        float lr = __shfl(l_s, quad * 4 + r, 16);
        float inv = 1.0f / lr;
        long row = qbase + wave * 16 + quad * 4 + r;
        #pragma unroll
        for (int t = 0; t < 8; t++)
            o[row * HDIM + head * 128 + t * 16 + lrow] = (half_t)(oacc[t][r] * inv);
    }
}

extern "C" void kernel_launch(void* const* d_in, const int* in_sizes, int n_in,
                              void* d_out, int out_size, void* d_ws, size_t ws_size,
                              hipStream_t stream) {
    const float* hidden = (const float*)d_in[0];
    const float* cosT   = (const float*)d_in[1];
    const float* sinT   = (const float*)d_in[2];
    const int*   doc    = (const int*)d_in[3];
    // d_in[4] = position_ids (unused; cos/sin precomputed)
    const float* Wq = (const float*)d_in[5];
    const float* bq = (const float*)d_in[6];
    const float* Wk = (const float*)d_in[7];
    const float* bk = (const float*)d_in[8];
    const float* Wv = (const float*)d_in[9];
    const float* bv = (const float*)d_in[10];
    const float* Wo = (const float*)d_in[11];
    float* out = (float*)d_out;

    // f16 workspace layout (halves); ~93 MB + tail pad (the GEMM pipeline
    // prefetches 2 garbage K-tiles past the end of the last operand).
    // Po (oproj f16 partials, 14.7M halves) aliases wqh..wkh (dead at oproj).
    half_t* hh  = (half_t*)d_ws;                   // dead after qkv; o reuses it
    half_t* q   = hh  + (size_t)S_LEN * HDIM;
    half_t* k   = q   + (size_t)S_LEN * HDIM;
    half_t* vt  = k   + (size_t)S_LEN * KVDIM;
    half_t* woh = vt  + (size_t)KVDIM * S_LEN;
    half_t* wqh = woh + (size_t)HDIM * HDIM;
    half_t* wkh = wqh + (size_t)HDIM * HDIM;
    half_t* wvh = wkh + (size_t)KVDIM * HDIM;      // followed by tail pad
    half_t* o   = hh;            // alias: hh dead once qkv_kernel completes
    half_t* Po  = wqh;           // alias: weights dead at oproj time

    cvt_kernel<<<4480, 256, 0, stream>>>(hidden, Wq, Wk, Wv, Wo, hh, wqh, wkh, wvh, woh);
    qkv_kernel<<<dim3(8, 18), 512, 0, stream>>>(hh, wqh, bq, wkh, bk, wvh, bv, q, k, vt);
    rope_kernel<<<16384, 256, 0, stream>>>(q, k, cosT, sinT);
    attn_kernel<<<dim3(32, NHEADS), 256, 0, stream>>>(q, k, vt, doc, o);
    oproj_kernel<<<dim3(8, 14, 2), 512, 0, stream>>>(o, woh, Po);
    oreduce_kernel<<<7168, 256, 0, stream>>>(Po, out);
}